// Round 1
// baseline (1019.092 us; speedup 1.0000x reference)
//
#include <hip/hip_runtime.h>
#include <math.h>

typedef short bf16x8 __attribute__((ext_vector_type(8)));
typedef float f32x4 __attribute__((ext_vector_type(4)));
typedef unsigned short u16;

#define AS1 __attribute__((address_space(1)))
#define AS3 __attribute__((address_space(3)))

constexpr int kB = 16, kT = 1024, kS = 2048, kH = 1024;
constexpr long NTH = (long)kB * kT * kH;  // 16.8M elems (33.5 MB bf16, 67 MB fp32)
constexpr long NSH = (long)kB * kS * kH;  // 33.6M elems (67 MB bf16)

// ---------------- bf16 helpers ----------------
__device__ __forceinline__ u16 bf16_rne(float x) {
    unsigned u = __float_as_uint(x);
    u += 0x7FFFu + ((u >> 16) & 1u);
    return (u16)(u >> 16);
}
__device__ __forceinline__ float bf16_f32(u16 h) {
    return __uint_as_float(((unsigned)h) << 16);
}
__device__ __forceinline__ void split2(float x, u16& hi, u16& lo) {
    hi = bf16_rne(x);
    lo = bf16_rne(x - bf16_f32(hi));
}

// ---------------- async staging: 128x32 u16 row-major tile via global_load_lds ----------
// LDS dest is wave-uniform base + lane*16B (hardware); global src is per-lane.
// Linear LDS order == row-major [128][32] tile order (verified: u16 off = unit*8).
__device__ __forceinline__ void stage_gll(const u16* __restrict__ g, long ld, int t, u16* dst) {
    const int wave = t >> 6;
#pragma unroll
    for (int it = 0; it < 2; ++it) {
        const int u = it * 256 + t;                       // 16B-unit index, 0..511
        const u16* src = g + (long)(u >> 2) * ld + ((u & 3) << 3);
        u16* l = dst + ((it << 2) + wave) * 512;          // wave-uniform chunk base
        __builtin_amdgcn_global_load_lds((AS1 void*)src, (AS3 void*)l, 16, 0, 0);
    }
}

// ---------------- MFMA inner compute ----------------
// Wave computes 64x64: 4x4 tiles of 16x16; A/B frag: lane holds X[idx&15][quad*8+j]
__device__ __forceinline__ void mma_plain(const u16* As, const u16* Bs, f32x4 acc[4][4],
                                          int wr, int wc, int l15, int quad) {
    bf16x8 a[4], b[4];
#pragma unroll
    for (int i = 0; i < 4; ++i)
        a[i] = *(const bf16x8*)(As + (wr * 64 + i * 16 + l15) * 32 + quad * 8);
#pragma unroll
    for (int j = 0; j < 4; ++j)
        b[j] = *(const bf16x8*)(Bs + (wc * 64 + j * 16 + l15) * 32 + quad * 8);
#pragma unroll
    for (int i = 0; i < 4; ++i)
#pragma unroll
        for (int j = 0; j < 4; ++j)
            acc[i][j] = __builtin_amdgcn_mfma_f32_16x16x32_bf16(a[i], b[j], acc[i][j], 0, 0, 0);
}

__device__ __forceinline__ void mma_split(const u16* Ah, const u16* Al,
                                          const u16* Bh, const u16* Bl, f32x4 acc[4][4],
                                          int wr, int wc, int l15, int quad) {
    bf16x8 ah[4], al[4], bh[4], bl[4];
#pragma unroll
    for (int i = 0; i < 4; ++i) {
        int off = (wr * 64 + i * 16 + l15) * 32 + quad * 8;
        ah[i] = *(const bf16x8*)(Ah + off);
        al[i] = *(const bf16x8*)(Al + off);
    }
#pragma unroll
    for (int j = 0; j < 4; ++j) {
        int off = (wc * 64 + j * 16 + l15) * 32 + quad * 8;
        bh[j] = *(const bf16x8*)(Bh + off);
        bl[j] = *(const bf16x8*)(Bl + off);
    }
#pragma unroll
    for (int i = 0; i < 4; ++i)
#pragma unroll
        for (int j = 0; j < 4; ++j) {
            acc[i][j] = __builtin_amdgcn_mfma_f32_16x16x32_bf16(ah[i], bh[j], acc[i][j], 0, 0, 0);
            acc[i][j] = __builtin_amdgcn_mfma_f32_16x16x32_bf16(ah[i], bl[j], acc[i][j], 0, 0, 0);
            acc[i][j] = __builtin_amdgcn_mfma_f32_16x16x32_bf16(al[i], bh[j], acc[i][j], 0, 0, 0);
        }
}

// ---------------- prepass: fp32 -> split bf16 hi/lo (grid-stride, float4) ----------------
__global__ __launch_bounds__(256) void split_f32(const float* __restrict__ src,
                                                 u16* __restrict__ hi, u16* __restrict__ lo,
                                                 long n4) {
    for (long i = (long)blockIdx.x * 256 + threadIdx.x; i < n4; i += (long)gridDim.x * 256) {
        float4 v = ((const float4*)src)[i];
        u16 h0, l0, h1, l1, h2, l2, h3, l3;
        split2(v.x, h0, l0); split2(v.y, h1, l1);
        split2(v.z, h2, l2); split2(v.w, h3, l3);
        ((ushort4*)hi)[i] = make_ushort4(h0, h1, h2, h3);
        ((ushort4*)lo)[i] = make_ushort4(l0, l1, l2, l3);
    }
}

// ---------------- prepass: fp32 -> bf16 rne ----------------
__global__ __launch_bounds__(256) void cvt_f32(const float* __restrict__ src,
                                               u16* __restrict__ dst, long n4) {
    for (long i = (long)blockIdx.x * 256 + threadIdx.x; i < n4; i += (long)gridDim.x * 256) {
        float4 v = ((const float4*)src)[i];
        ((ushort4*)dst)[i] = make_ushort4(bf16_rne(v.x), bf16_rne(v.y),
                                          bf16_rne(v.z), bf16_rne(v.w));
    }
}

// ---------------- 16B copy (grid-stride) ----------------
__global__ __launch_bounds__(256) void copy16(const uint4* __restrict__ src,
                                              uint4* __restrict__ dst, long n) {
    for (long i = (long)blockIdx.x * 256 + threadIdx.x; i < n; i += (long)gridDim.x * 256)
        dst[i] = src[i];
}

// ---------------- ctx transpose+convert: [B,S,H] fp32 -> [B,H,S] bf16 ----------------
__global__ __launch_bounds__(256) void transpose_ctx(const float* __restrict__ ctx,
                                                     u16* __restrict__ ctxT) {
    __shared__ u16 tile[64 * 72];  // [h][s], pitch 72 (16B-aligned rows)
    const int t = threadIdx.x;
    const float* src = ctx + (long)blockIdx.z * kS * kH + (long)(blockIdx.y * 64) * kH
                       + blockIdx.x * 64;
#pragma unroll
    for (int it = 0; it < 4; ++it) {
        int idx = it * 256 + t;              // 1024 float4 chunks = 64 s-rows x 16
        int s = idx >> 4, hq = (idx & 15) << 2;
        float4 v = *(const float4*)(src + (long)s * kH + hq);
        tile[(hq + 0) * 72 + s] = bf16_rne(v.x);
        tile[(hq + 1) * 72 + s] = bf16_rne(v.y);
        tile[(hq + 2) * 72 + s] = bf16_rne(v.z);
        tile[(hq + 3) * 72 + s] = bf16_rne(v.w);
    }
    __syncthreads();
    u16* dst = ctxT + (long)blockIdx.z * kH * kS + (long)(blockIdx.x * 64) * kS
               + blockIdx.y * 64;
#pragma unroll
    for (int it = 0; it < 2; ++it) {
        int idx = it * 256 + t;              // 512 8-u16 chunks = 64 h-rows x 8
        int h = idx >> 3, sq = (idx & 7) << 3;
        *(uint4*)(dst + (long)h * kS + sq) = *(const uint4*)&tile[h * 72 + sq];
    }
}

// ---------------- GEMM1: q = output @ attn_w^T (all-bf16 split, gll staging) ----------
__global__ __launch_bounds__(256) void gemm_q(const u16* __restrict__ Ahg,
                                              const u16* __restrict__ Alg,
                                              const u16* __restrict__ Bhg,
                                              const u16* __restrict__ Blg,
                                              u16* __restrict__ Qhi, u16* __restrict__ Qlo) {
    __shared__ u16 Ah[128 * 32], Al[128 * 32], Bh[128 * 32], Bl[128 * 32];
    const int t = threadIdx.x, lane = t & 63, wave = t >> 6;
    const int wr = wave >> 1, wc = wave & 1, l15 = lane & 15, quad = lane >> 4;
    const long bm = blockIdx.y * 128, bn = blockIdx.x * 128;

    f32x4 acc[4][4] = {};
    for (int k0 = 0; k0 < kH; k0 += 32) {
        stage_gll(Ahg + bm * kH + k0, kH, t, Ah);
        stage_gll(Alg + bm * kH + k0, kH, t, Al);
        stage_gll(Bhg + bn * kH + k0, kH, t, Bh);
        stage_gll(Blg + bn * kH + k0, kH, t, Bl);
        __syncthreads();
        mma_split(Ah, Al, Bh, Bl, acc, wr, wc, l15, quad);
        __syncthreads();
    }
#pragma unroll
    for (int i = 0; i < 4; ++i)
#pragma unroll
        for (int j = 0; j < 4; ++j)
#pragma unroll
            for (int r = 0; r < 4; ++r) {
                long m = bm + wr * 64 + i * 16 + quad * 4 + r;
                long n = bn + wc * 64 + j * 16 + l15;
                float v = acc[i][j][r];
                u16 h = bf16_rne(v);
                Qhi[m * kH + n] = h;
                Qlo[m * kH + n] = bf16_rne(v - bf16_f32(h));
            }
}

// ---------------- GEMM2: logits = q @ ctx^T per batch (all-bf16 split, gll) ----------
__global__ __launch_bounds__(256) void gemm_logits(const u16* __restrict__ Qhi,
                                                   const u16* __restrict__ Qlo,
                                                   const u16* __restrict__ Chi,
                                                   const u16* __restrict__ Clo,
                                                   float* __restrict__ Cout) {
    __shared__ u16 Ah[128 * 32], Al[128 * 32], Bh[128 * 32], Bl[128 * 32];
    const int t = threadIdx.x, lane = t & 63, wave = t >> 6;
    const int wr = wave >> 1, wc = wave & 1, l15 = lane & 15, quad = lane >> 4;
    const int z = blockIdx.z;
    const long bm = blockIdx.y * 128, bn = blockIdx.x * 128;
    const u16* qh = Qhi + (long)z * kT * kH;
    const u16* ql = Qlo + (long)z * kT * kH;
    const u16* ch = Chi + (long)z * kS * kH;
    const u16* cl = Clo + (long)z * kS * kH;
    float* C = Cout + (long)z * kT * kS;

    f32x4 acc[4][4] = {};
    for (int k0 = 0; k0 < kH; k0 += 32) {
        stage_gll(qh + bm * kH + k0, kH, t, Ah);
        stage_gll(ql + bm * kH + k0, kH, t, Al);
        stage_gll(ch + bn * kH + k0, kH, t, Bh);
        stage_gll(cl + bn * kH + k0, kH, t, Bl);
        __syncthreads();
        mma_split(Ah, Al, Bh, Bl, acc, wr, wc, l15, quad);
        __syncthreads();
    }
#pragma unroll
    for (int i = 0; i < 4; ++i)
#pragma unroll
        for (int j = 0; j < 4; ++j)
#pragma unroll
            for (int r = 0; r < 4; ++r) {
                long m = bm + wr * 64 + i * 16 + quad * 4 + r;
                long n = bn + wc * 64 + j * 16 + l15;
                C[m * kS + n] = acc[i][j][r];
            }
}

// ---------------- softmax over S, in place; also emits bf16 copy ----------------
__global__ __launch_bounds__(256) void softmax_rows(float* __restrict__ P,
                                                    u16* __restrict__ Pb) {
    __shared__ float red[4];
    float* p = P + (long)blockIdx.x * kS;
    u16* pb = Pb + (long)blockIdx.x * kS;
    const int t = threadIdx.x;

    float4 v0 = ((const float4*)p)[t];
    float4 v1 = ((const float4*)p)[t + 256];

    float m = fmaxf(fmaxf(fmaxf(v0.x, v0.y), fmaxf(v0.z, v0.w)),
                    fmaxf(fmaxf(v1.x, v1.y), fmaxf(v1.z, v1.w)));
#pragma unroll
    for (int o = 32; o > 0; o >>= 1) m = fmaxf(m, __shfl_xor(m, o));
    if ((t & 63) == 0) red[t >> 6] = m;
    __syncthreads();
    m = fmaxf(fmaxf(red[0], red[1]), fmaxf(red[2], red[3]));
    __syncthreads();

    v0.x = expf(v0.x - m); v0.y = expf(v0.y - m);
    v0.z = expf(v0.z - m); v0.w = expf(v0.w - m);
    v1.x = expf(v1.x - m); v1.y = expf(v1.y - m);
    v1.z = expf(v1.z - m); v1.w = expf(v1.w - m);

    float s = v0.x + v0.y + v0.z + v0.w + v1.x + v1.y + v1.z + v1.w;
#pragma unroll
    for (int o = 32; o > 0; o >>= 1) s += __shfl_xor(s, o);
    if ((t & 63) == 0) red[t >> 6] = s;
    __syncthreads();
    s = red[0] + red[1] + red[2] + red[3];

    const float inv = 1.0f / s;
    v0.x *= inv; v0.y *= inv; v0.z *= inv; v0.w *= inv;
    v1.x *= inv; v1.y *= inv; v1.z *= inv; v1.w *= inv;

    ((float4*)p)[t]       = v0;
    ((float4*)p)[t + 256] = v1;
    ((ushort4*)pb)[t]       = make_ushort4(bf16_rne(v0.x), bf16_rne(v0.y),
                                           bf16_rne(v0.z), bf16_rne(v0.w));
    ((ushort4*)pb)[t + 256] = make_ushort4(bf16_rne(v1.x), bf16_rne(v1.y),
                                           bf16_rne(v1.z), bf16_rne(v1.w));
}

// ---------------- GEMM4: mix = attn @ ctx per batch (all-bf16, gll) ----------------
__global__ __launch_bounds__(256) void gemm_mix(const u16* __restrict__ attnb,
                                                const u16* __restrict__ ctxT,
                                                u16* __restrict__ Mixb) {
    __shared__ u16 As[128 * 32], Bs[128 * 32];
    const int t = threadIdx.x, lane = t & 63, wave = t >> 6;
    const int wr = wave >> 1, wc = wave & 1, l15 = lane & 15, quad = lane >> 4;
    const int z = blockIdx.z;
    const long bm = blockIdx.y * 128, bn = blockIdx.x * 128;
    const u16* Ab = attnb + (long)z * kT * kS;
    const u16* Bb = ctxT + (long)z * kH * kS;
    u16* C = Mixb + (long)z * kT * kH;

    f32x4 acc[4][4] = {};
    for (int k0 = 0; k0 < kS; k0 += 32) {
        stage_gll(Ab + bm * kS + k0, kS, t, As);
        stage_gll(Bb + bn * kS + k0, kS, t, Bs);
        __syncthreads();
        mma_plain(As, Bs, acc, wr, wc, l15, quad);
        __syncthreads();
    }
#pragma unroll
    for (int i = 0; i < 4; ++i)
#pragma unroll
        for (int j = 0; j < 4; ++j)
#pragma unroll
            for (int r = 0; r < 4; ++r) {
                long m = bm + wr * 64 + i * 16 + quad * 4 + r;
                long n = bn + wc * 64 + j * 16 + l15;
                C[m * kH + n] = bf16_rne(acc[i][j][r]);
            }
}

// ---------------- GEMM5: out = tanh([mix|q] @ lw^T + lb) (all-bf16, gll) ----------
__global__ __launch_bounds__(256) void gemm_out(const u16* __restrict__ Mixc,
                                                const u16* __restrict__ Qc,
                                                const u16* __restrict__ Wb,
                                                const float* __restrict__ bias,
                                                float* __restrict__ Out) {
    __shared__ u16 As[128 * 32], Bs[128 * 32];
    const int t = threadIdx.x, lane = t & 63, wave = t >> 6;
    const int wr = wave >> 1, wc = wave & 1, l15 = lane & 15, quad = lane >> 4;
    const long bm = blockIdx.y * 128, bn = blockIdx.x * 128;

    f32x4 acc[4][4] = {};
    for (int k0 = 0; k0 < 2 * kH; k0 += 32) {
        const u16* Ab = (k0 < kH) ? (Mixc + bm * kH + k0) : (Qc + bm * kH + (k0 - kH));
        stage_gll(Ab, kH, t, As);
        stage_gll(Wb + bn * (2 * kH) + k0, 2 * kH, t, Bs);
        __syncthreads();
        mma_plain(As, Bs, acc, wr, wc, l15, quad);
        __syncthreads();
    }
#pragma unroll
    for (int j = 0; j < 4; ++j) {
        long n = bn + wc * 64 + j * 16 + l15;
        float bj = bias[n];
#pragma unroll
        for (int i = 0; i < 4; ++i)
#pragma unroll
            for (int r = 0; r < 4; ++r) {
                long m = bm + wr * 64 + i * 16 + quad * 4 + r;
                Out[m * kH + n] = tanhf(acc[i][j][r] + bj);
            }
    }
}

// ---------------------------------------------------------------------------
// Buffer lifetime plan (ws = 128 MiB exactly; d_out = out 67MB | attn 134MB):
//   phase 1: ws = [ctx_hi | ctx_lo]            (split ctx, whole ws)
//            d_out.attn = [out_hi|out_lo|aw_hi|aw_lo]   (scratch, 71MB of 134)
//            d_out.out  = [q_hi | q_lo]        (gemm_q result)
//   gemm_logits overwrites d_out.attn with fp32 logits (reads q + ctx split).
//   phase 2: ws = [ctxT | attn_bf16]  (ctx split dead)
//            gemm_mix -> mixb into q_lo slot (q_lo dead after logits)
//   phase 3: copy [q_hi|mixb] (contiguous 67MB) -> ws[0:67MB] = [q_c | mix_c]
//            lwb (bf16 W) -> ws + 2*NTH (attn_bf16 slot, dead)
//            gemm_out reads ws only, writes d_out.out (q scratch dead).
extern "C" void kernel_launch(void* const* d_in, const int* in_sizes, int n_in,
                              void* d_out, int out_size, void* d_ws, size_t ws_size,
                              hipStream_t stream) {
    (void)in_sizes; (void)n_in; (void)out_size; (void)ws_size;

    const float* outp = (const float*)d_in[0];  // [B,T,H]
    const float* ctx  = (const float*)d_in[1];  // [B,S,H]
    const float* aw   = (const float*)d_in[2];  // [H,H]
    const float* lw   = (const float*)d_in[3];  // [H,2H]
    const float* lb   = (const float*)d_in[4];  // [H]

    float* out  = (float*)d_out;                 // [B,T,H]
    float* attn = out + NTH;                     // [B,T,S]

    u16* ws = (u16*)d_ws;
    // phase 1
    u16* ctx_hi = ws;
    u16* ctx_lo = ws + NSH;
    u16* q_hi = (u16*)out;
    u16* q_lo = q_hi + NTH;
    u16* oh  = (u16*)attn;
    u16* ol  = oh + NTH;
    u16* awh = ol + NTH;
    u16* awl = awh + (long)kH * kH;
    // phase 2
    u16* ctxT  = ws;           // [B,H,S] bf16
    u16* attnb = ws + NSH;     // [B,T,S] bf16
    u16* mixb  = q_lo;         // [B,T,H] bf16
    // phase 3
    u16* q_c   = ws;           // copy of q_hi
    u16* mix_c = ws + NTH;     // copy of mixb
    u16* lwb   = ws + 2 * NTH; // [H,2H] bf16

    split_f32<<<2048, 256, 0, stream>>>(ctx, ctx_hi, ctx_lo, NSH / 4);
    split_f32<<<2048, 256, 0, stream>>>(outp, oh, ol, NTH / 4);
    split_f32<<<1024, 256, 0, stream>>>(aw, awh, awl, (long)kH * kH / 4);

    gemm_q<<<dim3(kH / 128, (kB * kT) / 128), 256, 0, stream>>>(oh, ol, awh, awl, q_hi, q_lo);
    gemm_logits<<<dim3(kS / 128, kT / 128, kB), 256, 0, stream>>>(q_hi, q_lo, ctx_hi, ctx_lo,
                                                                  attn);
    softmax_rows<<<kB * kT, 256, 0, stream>>>(attn, attnb);
    transpose_ctx<<<dim3(kH / 64, kS / 64, kB), 256, 0, stream>>>(ctx, ctxT);
    gemm_mix<<<dim3(kH / 128, kT / 128, kB), 256, 0, stream>>>(attnb, ctxT, mixb);

    copy16<<<2048, 256, 0, stream>>>((const uint4*)q_hi, (uint4*)ws, (2 * NTH) / 8);
    cvt_f32<<<2048, 256, 0, stream>>>(lw, lwb, (long)kH * 2 * kH / 4);

    gemm_out<<<dim3(kH / 128, (kB * kT) / 128), 256, 0, stream>>>(mix_c, q_c, lwb, lb, out);
}

// Round 2
// 891.346 us; speedup vs baseline: 1.1433x; 1.1433x over previous
//
#include <hip/hip_runtime.h>
#include <math.h>

typedef short bf16x8 __attribute__((ext_vector_type(8)));
typedef float f32x4 __attribute__((ext_vector_type(4)));
typedef unsigned short u16;

#define AS1 __attribute__((address_space(1)))
#define AS3 __attribute__((address_space(3)))

constexpr int kB = 16, kT = 1024, kS = 2048, kH = 1024;
constexpr long NTH = (long)kB * kT * kH;  // 16.8M elems
constexpr long NSH = (long)kB * kS * kH;  // 33.6M elems

// ---------------- bf16 helpers ----------------
__device__ __forceinline__ u16 bf16_rne(float x) {
    unsigned u = __float_as_uint(x);
    u += 0x7FFFu + ((u >> 16) & 1u);
    return (u16)(u >> 16);
}
__device__ __forceinline__ float bf16_f32(u16 h) {
    return __uint_as_float(((unsigned)h) << 16);
}
__device__ __forceinline__ void split2(float x, u16& hi, u16& lo) {
    hi = bf16_rne(x);
    lo = bf16_rne(x - bf16_f32(hi));
}

// =========================================================================
// 256x256x(BK=64) 8-wave GEMM core, double-buffered 128 KiB LDS,
// global_load_lds staging (linear dest + inverse-swizzled source),
// XOR-swizzled ds_read (T2), counted vmcnt (T4), setprio (T5).
// Swizzle: logical (row, colbyte) lives at LDS byte row*128 + (colbyte ^ ((row&7)<<4)).
// =========================================================================

// Stage one 256x64 bf16 tile (32 KiB) = 4 chunks x (512 thr x 16B).
__device__ __forceinline__ void stage_mat(const u16* __restrict__ g, long ld,
                                          u16* lds, int t, int wave) {
#pragma unroll
    for (int c = 0; c < 4; ++c) {
        int u = c * 512 + t;          // 16B unit, 8 per 128B row
        int r = u >> 3, j = u & 7;
        const u16* src = g + (long)r * ld + ((j ^ (r & 7)) << 3);  // inverse swizzle
        u16* dst = lds + c * 4096 + wave * 512;                    // linear dest
        __builtin_amdgcn_global_load_lds((AS1 void*)src, (AS3 void*)dst, 16, 0, 0);
    }
}

// Compute one 256x256 @ K=64 tile: 64 MFMA/wave, reads swizzled LDS.
__device__ __forceinline__ void tile_compute(const u16* As, const u16* Bs,
                                             f32x4 acc[8][4], int wr, int wc,
                                             int l15, int cbu0, int cbu1) {
    bf16x8 b[4][2];
#pragma unroll
    for (int j = 0; j < 4; ++j) {
        const u16* base = Bs + (wc * 64 + j * 16 + l15) * 64;
        b[j][0] = *(const bf16x8*)(base + cbu0);
        b[j][1] = *(const bf16x8*)(base + cbu1);
    }
#pragma unroll
    for (int qm = 0; qm < 2; ++qm) {
        bf16x8 a[4][2];
#pragma unroll
        for (int i = 0; i < 4; ++i) {
            const u16* base = As + (wr * 128 + qm * 64 + i * 16 + l15) * 64;
            a[i][0] = *(const bf16x8*)(base + cbu0);
            a[i][1] = *(const bf16x8*)(base + cbu1);
        }
        __builtin_amdgcn_s_setprio(1);
#pragma unroll
        for (int i = 0; i < 4; ++i)
#pragma unroll
            for (int j = 0; j < 4; ++j) {
                acc[qm * 4 + i][j] = __builtin_amdgcn_mfma_f32_16x16x32_bf16(
                    a[i][0], b[j][0], acc[qm * 4 + i][j], 0, 0, 0);
                acc[qm * 4 + i][j] = __builtin_amdgcn_mfma_f32_16x16x32_bf16(
                    a[i][1], b[j][1], acc[qm * 4 + i][j], 0, 0, 0);
            }
        __builtin_amdgcn_s_setprio(0);
    }
}

#define WAIT_VM(N)                                            \
    asm volatile("s_waitcnt vmcnt(" #N ")" ::: "memory");     \
    __builtin_amdgcn_s_barrier();                             \
    __builtin_amdgcn_sched_barrier(0);

#define POST_BARRIER()                                        \
    __builtin_amdgcn_sched_barrier(0);                        \
    __builtin_amdgcn_s_barrier();                             \
    __builtin_amdgcn_sched_barrier(0);

// NT = K'/64 tiles; TPS = tiles per K-segment. Sources pre-offset to (bm,bn).
template <int NT, int TPS>
__device__ __forceinline__ void gemm_core(const u16* a0, const u16* a1, const u16* a2,
                                          long lda,
                                          const u16* b0, const u16* b1, const u16* b2,
                                          long ldb, f32x4 acc[8][4]) {
    __shared__ u16 As[2][256 * 64], Bs[2][256 * 64];
    const int t = threadIdx.x, lane = t & 63, wave = t >> 6;
    const int wr = wave >> 2, wc = wave & 3, l15 = lane & 15, quad = lane >> 4;
    const int swzb = (l15 & 7) << 4;
    const int cbu0 = ((quad * 16) ^ swzb) >> 1;        // u16 offset, k-half 0
    const int cbu1 = ((quad * 16 + 64) ^ swzb) >> 1;   // u16 offset, k-half 1

    auto srcA = [&](int kt) {
        int seg = kt / TPS;
        const u16* p = (seg == 0) ? a0 : (seg == 1 ? a1 : a2);
        return p + (long)(kt % TPS) * 64;
    };
    auto srcB = [&](int kt) {
        int seg = kt / TPS;
        const u16* p = (seg == 0) ? b0 : (seg == 1 ? b1 : b2);
        return p + (long)(kt % TPS) * 64;
    };

    // prologue: tiles 0 and 1 in flight (16 loads/thread)
    stage_mat(srcA(0), lda, As[0], t, wave);
    stage_mat(srcB(0), ldb, Bs[0], t, wave);
    __builtin_amdgcn_sched_barrier(0);
    stage_mat(srcA(1), lda, As[1], t, wave);
    stage_mat(srcB(1), ldb, Bs[1], t, wave);
    __builtin_amdgcn_sched_barrier(0);

#pragma unroll 1
    for (int it = 0; it < NT / 2 - 1; ++it) {
        int kt = 2 * it;
        WAIT_VM(8)                                   // tile kt resident (kt+1 in flight)
        tile_compute(As[0], Bs[0], acc, wr, wc, l15, cbu0, cbu1);
        POST_BARRIER()                               // all waves done reading buf0
        stage_mat(srcA(kt + 2), lda, As[0], t, wave);
        stage_mat(srcB(kt + 2), ldb, Bs[0], t, wave);

        WAIT_VM(8)                                   // tile kt+1 resident
        tile_compute(As[1], Bs[1], acc, wr, wc, l15, cbu0, cbu1);
        POST_BARRIER()
        stage_mat(srcA(kt + 3), lda, As[1], t, wave);
        stage_mat(srcB(kt + 3), ldb, Bs[1], t, wave);
    }
    // tail: tiles NT-2, NT-1 (already staged; no more prefetch)
    WAIT_VM(8)
    tile_compute(As[0], Bs[0], acc, wr, wc, l15, cbu0, cbu1);
    WAIT_VM(0)
    tile_compute(As[1], Bs[1], acc, wr, wc, l15, cbu0, cbu1);
}

// ---------------- GEMM kernels ----------------
// q = output @ attn_w^T in split precision: K' = 3H, segs (oh,awh),(ol,awh),(oh,awl)
__global__ __launch_bounds__(512, 2) void k_gemm_q(const u16* __restrict__ oh,
                                                   const u16* __restrict__ ol,
                                                   const u16* __restrict__ awh,
                                                   const u16* __restrict__ awl,
                                                   u16* __restrict__ Qhi,
                                                   u16* __restrict__ Qlo) {
    const long bm = (long)blockIdx.y * 256, bn = (long)blockIdx.x * 256;
    f32x4 acc[8][4] = {};
    gemm_core<48, 16>(oh + bm * kH, ol + bm * kH, oh + bm * kH, kH,
                      awh + bn * kH, awh + bn * kH, awl + bn * kH, kH, acc);
    const int t = threadIdx.x, lane = t & 63, wave = t >> 6;
    const int wr = wave >> 2, wc = wave & 3, l15 = lane & 15, quad = lane >> 4;
#pragma unroll
    for (int i = 0; i < 8; ++i)
#pragma unroll
        for (int j = 0; j < 4; ++j)
#pragma unroll
            for (int r = 0; r < 4; ++r) {
                long m = bm + wr * 128 + i * 16 + quad * 4 + r;
                long n = bn + wc * 64 + j * 16 + l15;
                float v = acc[i][j][r];
                u16 h = bf16_rne(v);
                Qhi[m * kH + n] = h;
                Qlo[m * kH + n] = bf16_rne(v - bf16_f32(h));
            }
}

// logits = q @ ctx^T per batch, split: K' = 3H, segs (qh,ch),(ql,ch),(qh,cl)
// 1D grid 512, XCD-aware decode: each XCD owns 2 whole batches.
__global__ __launch_bounds__(512, 2) void k_gemm_logits(const u16* __restrict__ Qh,
                                                        const u16* __restrict__ Ql,
                                                        const u16* __restrict__ Ch,
                                                        const u16* __restrict__ Cl,
                                                        float* __restrict__ Cout) {
    const int l = blockIdx.x;
    const int xcd = l & 7, slot = l >> 3;
    const int z = xcd + ((slot >> 5) << 3);
    const int inner = slot & 31;
    const long bn = (long)(inner & 7) * 256;   // S tiles (8)
    const long bm = (long)(inner >> 3) * 256;  // T tiles (4)
    const u16* qh = Qh + (long)z * kT * kH + bm * kH;
    const u16* ql = Ql + (long)z * kT * kH + bm * kH;
    const u16* ch = Ch + (long)z * kS * kH + bn * kH;
    const u16* cl = Cl + (long)z * kS * kH + bn * kH;
    f32x4 acc[8][4] = {};
    gemm_core<48, 16>(qh, ql, qh, kH, ch, ch, cl, kH, acc);
    float* C = Cout + (long)z * kT * kS;
    const int t = threadIdx.x, lane = t & 63, wave = t >> 6;
    const int wr = wave >> 2, wc = wave & 3, l15 = lane & 15, quad = lane >> 4;
#pragma unroll
    for (int i = 0; i < 8; ++i)
#pragma unroll
        for (int j = 0; j < 4; ++j)
#pragma unroll
            for (int r = 0; r < 4; ++r) {
                long m = bm + wr * 128 + i * 16 + quad * 4 + r;
                long n = bn + wc * 64 + j * 16 + l15;
                C[m * kS + n] = acc[i][j][r];
            }
}

// mix = attn @ ctx per batch (plain bf16): K' = S, single segment
__global__ __launch_bounds__(512, 2) void k_gemm_mix(const u16* __restrict__ attnb,
                                                     const u16* __restrict__ ctxT,
                                                     u16* __restrict__ Mixb) {
    const int l = blockIdx.x;
    const int xcd = l & 7, slot = l >> 3;
    const int z = xcd + ((slot >> 4) << 3);
    const int inner = slot & 15;
    const long bn = (long)(inner & 3) * 256;   // H tiles (4)
    const long bm = (long)(inner >> 2) * 256;  // T tiles (4)
    const u16* Ab = attnb + (long)z * kT * kS + bm * kS;
    const u16* Bb = ctxT + (long)z * kH * kS + bn * kS;
    f32x4 acc[8][4] = {};
    gemm_core<32, 32>(Ab, Ab, Ab, kS, Bb, Bb, Bb, kS, acc);
    u16* C = Mixb + (long)z * kT * kH;
    const int t = threadIdx.x, lane = t & 63, wave = t >> 6;
    const int wr = wave >> 2, wc = wave & 3, l15 = lane & 15, quad = lane >> 4;
#pragma unroll
    for (int i = 0; i < 8; ++i)
#pragma unroll
        for (int j = 0; j < 4; ++j)
#pragma unroll
            for (int r = 0; r < 4; ++r) {
                long m = bm + wr * 128 + i * 16 + quad * 4 + r;
                long n = bn + wc * 64 + j * 16 + l15;
                C[m * kH + n] = bf16_rne(acc[i][j][r]);
            }
}

// out = tanh([mix|q] @ lw^T + lb): K' = 2H, segs (mix,lw[:, :H]),(q,lw[:, H:])
__global__ __launch_bounds__(512, 2) void k_gemm_out(const u16* __restrict__ mixc,
                                                     const u16* __restrict__ qc,
                                                     const u16* __restrict__ lwb,
                                                     const float* __restrict__ bias,
                                                     float* __restrict__ Out) {
    const long bm = (long)blockIdx.y * 256, bn = (long)blockIdx.x * 256;
    f32x4 acc[8][4] = {};
    gemm_core<32, 16>(mixc + bm * kH, qc + bm * kH, qc + bm * kH, kH,
                      lwb + bn * 2 * kH, lwb + bn * 2 * kH + kH, lwb + bn * 2 * kH + kH,
                      2 * kH, acc);
    const int t = threadIdx.x, lane = t & 63, wave = t >> 6;
    const int wr = wave >> 2, wc = wave & 3, l15 = lane & 15, quad = lane >> 4;
#pragma unroll
    for (int j = 0; j < 4; ++j) {
        long n = bn + wc * 64 + j * 16 + l15;
        float bj = bias[n];
#pragma unroll
        for (int i = 0; i < 8; ++i)
#pragma unroll
            for (int r = 0; r < 4; ++r) {
                long m = bm + wr * 128 + i * 16 + quad * 4 + r;
                Out[m * kH + n] = tanhf(acc[i][j][r] + bj);
            }
    }
}

// ---------------- prepasses ----------------
__global__ __launch_bounds__(256) void split_f32(const float* __restrict__ src,
                                                 u16* __restrict__ hi, u16* __restrict__ lo,
                                                 long n4) {
    for (long i = (long)blockIdx.x * 256 + threadIdx.x; i < n4; i += (long)gridDim.x * 256) {
        float4 v = ((const float4*)src)[i];
        u16 h0, l0, h1, l1, h2, l2, h3, l3;
        split2(v.x, h0, l0); split2(v.y, h1, l1);
        split2(v.z, h2, l2); split2(v.w, h3, l3);
        ((ushort4*)hi)[i] = make_ushort4(h0, h1, h2, h3);
        ((ushort4*)lo)[i] = make_ushort4(l0, l1, l2, l3);
    }
}

__global__ __launch_bounds__(256) void cvt_f32(const float* __restrict__ src,
                                               u16* __restrict__ dst, long n4) {
    for (long i = (long)blockIdx.x * 256 + threadIdx.x; i < n4; i += (long)gridDim.x * 256) {
        float4 v = ((const float4*)src)[i];
        ((ushort4*)dst)[i] = make_ushort4(bf16_rne(v.x), bf16_rne(v.y),
                                          bf16_rne(v.z), bf16_rne(v.w));
    }
}

__global__ __launch_bounds__(256) void copy16(const uint4* __restrict__ src,
                                              uint4* __restrict__ dst, long n) {
    for (long i = (long)blockIdx.x * 256 + threadIdx.x; i < n; i += (long)gridDim.x * 256)
        dst[i] = src[i];
}

// bf16 [B,S,H] -> [B,H,S] (ctxT == transpose of ctx_hi bit-exactly)
__global__ __launch_bounds__(256) void transpose_bf16(const u16* __restrict__ in,
                                                      u16* __restrict__ outp) {
    __shared__ u16 tile[64 * 72];
    const int t = threadIdx.x;
    const u16* src = in + (long)blockIdx.z * kS * kH + (long)(blockIdx.y * 64) * kH
                     + blockIdx.x * 64;
#pragma unroll
    for (int it = 0; it < 2; ++it) {
        int idx = it * 256 + t;            // 512 chunks of 8 u16 = 64 s-rows x 8
        int s = idx >> 3, hc = (idx & 7) << 3;
        uint4 v = *(const uint4*)(src + (long)s * kH + hc);
        const u16* pv = (const u16*)&v;
#pragma unroll
        for (int k = 0; k < 8; ++k) tile[(hc + k) * 72 + s] = pv[k];
    }
    __syncthreads();
    u16* dst = outp + (long)blockIdx.z * kH * kS + (long)(blockIdx.x * 64) * kS
               + blockIdx.y * 64;
#pragma unroll
    for (int it = 0; it < 2; ++it) {
        int idx = it * 256 + t;
        int h = idx >> 3, sc = (idx & 7) << 3;
        *(uint4*)(dst + (long)h * kS + sc) = *(const uint4*)&tile[h * 72 + sc];
    }
}

// ---------------- softmax over S, in place; emits bf16 copy ----------------
__global__ __launch_bounds__(256) void softmax_rows(float* __restrict__ P,
                                                    u16* __restrict__ Pb) {
    __shared__ float red[4];
    float* p = P + (long)blockIdx.x * kS;
    u16* pb = Pb + (long)blockIdx.x * kS;
    const int t = threadIdx.x;

    float4 v0 = ((const float4*)p)[t];
    float4 v1 = ((const float4*)p)[t + 256];

    float m = fmaxf(fmaxf(fmaxf(v0.x, v0.y), fmaxf(v0.z, v0.w)),
                    fmaxf(fmaxf(v1.x, v1.y), fmaxf(v1.z, v1.w)));
#pragma unroll
    for (int o = 32; o > 0; o >>= 1) m = fmaxf(m, __shfl_xor(m, o));
    if ((t & 63) == 0) red[t >> 6] = m;
    __syncthreads();
    m = fmaxf(fmaxf(red[0], red[1]), fmaxf(red[2], red[3]));
    __syncthreads();

    v0.x = expf(v0.x - m); v0.y = expf(v0.y - m);
    v0.z = expf(v0.z - m); v0.w = expf(v0.w - m);
    v1.x = expf(v1.x - m); v1.y = expf(v1.y - m);
    v1.z = expf(v1.z - m); v1.w = expf(v1.w - m);

    float s = v0.x + v0.y + v0.z + v0.w + v1.x + v1.y + v1.z + v1.w;
#pragma unroll
    for (int o = 32; o > 0; o >>= 1) s += __shfl_xor(s, o);
    if ((t & 63) == 0) red[t >> 6] = s;
    __syncthreads();
    s = red[0] + red[1] + red[2] + red[3];

    const float inv = 1.0f / s;
    v0.x *= inv; v0.y *= inv; v0.z *= inv; v0.w *= inv;
    v1.x *= inv; v1.y *= inv; v1.z *= inv; v1.w *= inv;

    ((float4*)p)[t]       = v0;
    ((float4*)p)[t + 256] = v1;
    ((ushort4*)pb)[t]       = make_ushort4(bf16_rne(v0.x), bf16_rne(v0.y),
                                           bf16_rne(v0.z), bf16_rne(v0.w));
    ((ushort4*)pb)[t + 256] = make_ushort4(bf16_rne(v1.x), bf16_rne(v1.y),
                                           bf16_rne(v1.z), bf16_rne(v1.w));
}

// ---------------------------------------------------------------------------
// Lifetime plan (ws = 128 MiB; d_out = out 67MB | attn 134MB):
//  1. ws = [ctx_hi | ctx_lo]; attn-region scratch = [oh|ol|awh|awl]
//  2. k_gemm_q -> [q_hi|q_lo] in out-region
//  3. k_gemm_logits -> attn fp32 (overwrites oh/ol/aw scratch)
//  4. transpose_bf16: ctx_hi -> ctxT at ws[NSH:] (ctx_lo dead)
//  5. softmax: attn in place + attnb -> ws[0:NSH] (ctx_hi dead)
//  6. k_gemm_mix(attnb, ctxT) -> mixb = q_lo slot
//  7. copy [q_hi|mixb] -> ws[0:2*NTH] = [q_c|mix_c]; lwb -> ws+2*NTH (ctxT dead)
//  8. k_gemm_out(mix_c, q_c, lwb) -> out (q scratch dead)
extern "C" void kernel_launch(void* const* d_in, const int* in_sizes, int n_in,
                              void* d_out, int out_size, void* d_ws, size_t ws_size,
                              hipStream_t stream) {
    (void)in_sizes; (void)n_in; (void)out_size; (void)ws_size;

    const float* outp = (const float*)d_in[0];  // [B,T,H]
    const float* ctx  = (const float*)d_in[1];  // [B,S,H]
    const float* aw   = (const float*)d_in[2];  // [H,H]
    const float* lw   = (const float*)d_in[3];  // [H,2H]
    const float* lb   = (const float*)d_in[4];  // [H]

    float* out  = (float*)d_out;
    float* attn = out + NTH;

    u16* ws = (u16*)d_ws;
    u16* ctx_hi = ws;
    u16* ctx_lo = ws + NSH;
    u16* q_hi = (u16*)out;
    u16* q_lo = q_hi + NTH;
    u16* oh  = (u16*)attn;
    u16* ol  = oh + NTH;
    u16* awh = ol + NTH;
    u16* awl = awh + (long)kH * kH;
    u16* ctxT  = ws + NSH;
    u16* attnb = ws;
    u16* mixb  = q_lo;
    u16* q_c   = ws;
    u16* mix_c = ws + NTH;
    u16* lwb   = ws + 2 * NTH;

    split_f32<<<2048, 256, 0, stream>>>(ctx, ctx_hi, ctx_lo, NSH / 4);
    split_f32<<<2048, 256, 0, stream>>>(outp, oh, ol, NTH / 4);
    split_f32<<<1024, 256, 0, stream>>>(aw, awh, awl, (long)kH * kH / 4);

    k_gemm_q<<<dim3(kH / 256, (kB * kT) / 256), 512, 0, stream>>>(oh, ol, awh, awl,
                                                                  q_hi, q_lo);
    k_gemm_logits<<<512, 512, 0, stream>>>(q_hi, q_lo, ctx_hi, ctx_lo, attn);

    transpose_bf16<<<dim3(kH / 64, kS / 64, kB), 256, 0, stream>>>(ctx_hi, ctxT);
    softmax_rows<<<kB * kT, 256, 0, stream>>>(attn, attnb);

    k_gemm_mix<<<256, 512, 0, stream>>>(attnb, ctxT, mixb);

    copy16<<<2048, 256, 0, stream>>>((const uint4*)q_hi, (uint4*)ws, (2 * NTH) / 8);
    cvt_f32<<<2048, 256, 0, stream>>>(lw, lwb, (long)kH * 2 * kH / 4);

    k_gemm_out<<<dim3(kH / 256, (kB * kT) / 256), 512, 0, stream>>>(mix_c, q_c, lwb, lb, out);
}